// Round 10
// baseline (1353.288 us; speedup 1.0000x reference)
//
#include <hip/hip_runtime.h>
#include <hip/hip_bf16.h>

// MSAColumnAttention — R10: register diet to fit 128 total regs/wave ->
// __launch_bounds__(512,4) -> 2 blocks/CU, 16 waves (4/SIMD).
// Diet: no Wf[16] array (B-frag loaded per-kc, L1-hot), no bias16[16]
// (float2 bias pairs loaded at cvt_pk sites from L1-hot ball).
// R9 established: occupancy was reg-capped (128 VGPR + ~128 AGPR = 2 waves/SIMD),
// not LDS-capped. LDS 67.5KB already fits 2 blocks.
//
// 32x32x16 bf16 MFMA layouts (R4/R6-verified):
//   A[m][k]: lane(gg,j)=gg*32+j holds row m=j, k=8gg+e ; B likewise (col n=j)
//   D[m][n]: lane(gg,j) holds col n=j, rows m=(reg&3)+8*(reg>>2)+4*gg
// Fragment construction: 8x cvt_pk + 4x permlane32_swap per D-tile (verified).
//
// ws layout (total 202,117,120 B):
//   Wfrag [8][4][16 kc][64 lane][8 bf16] @0 (512 KB) | ball [1024] f32 @524288
//   oWhi @528384 | oWlo @659456 | xhat [196608][256] bf16 @790528
//   obuf [196608][256] bf16 @101453824   (gate staged here, then overwritten)

#define S_DIM 512
#define R_DIM 384
#define CM    256
#define NH    8
#define NROWS (S_DIM*R_DIM)

typedef unsigned short u16;
typedef unsigned int   u32;
typedef short bf16x8 __attribute__((ext_vector_type(8)));
typedef float f32x4  __attribute__((ext_vector_type(4)));
typedef float f32x16 __attribute__((ext_vector_type(16)));
typedef int   v2i    __attribute__((ext_vector_type(2)));

#define MFMA16(a,b,c) __builtin_amdgcn_mfma_f32_16x16x32_bf16((a),(b),(c),0,0,0)
#define MFMA32(a,b,c) __builtin_amdgcn_mfma_f32_32x32x16_bf16((a),(b),(c),0,0,0)

__device__ __forceinline__ float lo16f(u32 u){ return __uint_as_float(u << 16); }
__device__ __forceinline__ float hi16f(u32 u){ return __uint_as_float(u & 0xffff0000u); }
__device__ __forceinline__ float b2f(u16 x){ return __uint_as_float(((u32)x) << 16); }
__device__ __forceinline__ u16 f2bf(float f){
  u32 u = __float_as_uint(f);
  return (u16)((u + 0x7fffu + ((u >> 16) & 1u)) >> 16);   // RNE
}
__device__ __forceinline__ u32 pk2(float a, float b){
  return (u32)f2bf(a) | ((u32)f2bf(b) << 16);
}
__device__ __forceinline__ u32 cvtpk(float a, float b){
  u32 d;
  asm("v_cvt_pk_bf16_f32 %0, %1, %2" : "=v"(d) : "v"(a), "v"(b));
  return d;
}
__device__ __forceinline__ v2i pl32swap(u32 a, u32 b){
  return __builtin_amdgcn_permlane32_swap((int)a, (int)b, false, false);
}
__device__ __forceinline__ f32x16 zero16(){
  f32x16 z;
  #pragma unroll
  for(int q=0;q<16;q++) z[q]=0.f;
  return z;
}

#define SC2 0.2550348653f   // (1/sqrt(32)) * log2(e), folded into K at prep

// ---------------------------------------------------------------- prep_w ----
// blocks 0..1023 (h*128 + mat*32 + c): fold ln (and SC2 for K) into W row,
// write FRAG-ORDERED Wfrag[h][mat][kc][lane=gg*32+c][8] bf16; ball likewise.
// blocks 1024..1279: oW hi/lo split.
__global__ void prep_w(const float* __restrict__ lnw, const float* __restrict__ lnb,
                       const float* __restrict__ Wq, const float* __restrict__ Wk,
                       const float* __restrict__ Wv, const float* __restrict__ Wg,
                       const float* __restrict__ oW,
                       float* __restrict__ ball, u16* __restrict__ Wfrag,
                       u16* __restrict__ oWhi, u16* __restrict__ oWlo){
  int blk = blockIdx.x, t = threadIdx.x;
  if (blk < 1024){
    int h = blk >> 7, row = blk & 127, mat = row >> 5, c = row & 31;
    const float* Ws = (mat==0?Wq: mat==1?Wk: mat==2?Wv:Wg) + (size_t)(h*32+c)*CM;
    const float qs = (mat==1) ? SC2 : 1.f;   // fold softmax scale into K (f32, pre-round)
    float4 w4 = ((const float4*)Ws)[t];
    float4 l4 = ((const float4*)(lnw + (size_t)h*CM))[t];
    float4 b4 = ((const float4*)(lnb + (size_t)h*CM))[t];
    // elements k = 4t..4t+3 -> kc = t>>2, gg = (t>>1)&1, e0 = (t&1)*4
    int kc = t >> 2, gg = (t >> 1) & 1, e0 = (t & 1) * 4;
    u16* dst = Wfrag + ((size_t)(((blk>>5)*16 + kc))*64 + gg*32 + c)*8 + e0;  // blk>>5 = h*4+mat
    *(uint2*)dst = make_uint2(pk2(qs*w4.x*l4.x, qs*w4.y*l4.y),
                              pk2(qs*w4.z*l4.z, qs*w4.w*l4.w));
    float p = w4.x*b4.x + w4.y*b4.y + w4.z*b4.z + w4.w*b4.w;
    #pragma unroll
    for(int off=32; off; off>>=1) p += __shfl_down(p, off);
    if(t==0) ball[blk] = qs*p;
  } else {
    int m = blk - 1024;
    float4 w4 = ((const float4*)(oW + (size_t)m*CM))[t];
    u16 h0=f2bf(w4.x), h1=f2bf(w4.y), h2=f2bf(w4.z), h3=f2bf(w4.w);
    u16 l0=f2bf(w4.x-b2f(h0)), l1=f2bf(w4.y-b2f(h1));
    u16 l2=f2bf(w4.z-b2f(h2)), l3=f2bf(w4.w-b2f(h3));
    ((uint2*)(oWhi + (size_t)m*CM))[t] = make_uint2((u32)h0|((u32)h1<<16), (u32)h2|((u32)h3<<16));
    ((uint2*)(oWlo + (size_t)m*CM))[t] = make_uint2((u32)l0|((u32)l1<<16), (u32)l2|((u32)l3<<16));
  }
}

// ---------------------------------------------------------------- ln_xhat ----
__global__ __launch_bounds__(256) void ln_xhat(const float* __restrict__ msa,
                                               u16* __restrict__ xhat){
  const int tid = threadIdx.x;
  const int n0 = blockIdx.x*64;
  const int i = tid >> 2, p = tid & 3;
  const int n = n0 + i, rr = n >> 9, s = n & 511;
  const float* src = msa + ((size_t)s*R_DIM + rr)*CM + p*64;
  float x[64]; float sum=0.f, sq=0.f;
  #pragma unroll
  for(int j=0;j<64;j+=4){
    float4 v = *(const float4*)(src + j);
    x[j]=v.x; x[j+1]=v.y; x[j+2]=v.z; x[j+3]=v.w;
    sum += v.x+v.y+v.z+v.w;
    sq  += v.x*v.x + v.y*v.y + v.z*v.z + v.w*v.w;
  }
  sum += __shfl_xor(sum,1); sum += __shfl_xor(sum,2);
  sq  += __shfl_xor(sq,1);  sq  += __shfl_xor(sq,2);
  float mu = sum*(1.f/256.f);
  float rs = rsqrtf(sq*(1.f/256.f) - mu*mu + 1e-5f);
  u16* dst = xhat + (size_t)n*CM + p*64;
  #pragma unroll
  for(int j=0;j<64;j+=2)
    *(u32*)(dst + j) = pk2((x[j]-mu)*rs, (x[j+1]-mu)*rs);
}

// --------------------------------------------------------------- attn_fused6 ----
// 512 thr / 8 waves, 2 blocks/CU (67.5 KB LDS, <=128 total regs via diet).
// Wave w owns s-tiles {2w,2w+1}. proj: B-frag per-kc from Wfrag (L1-hot);
// Q->regs, K/V->LDS, G->obuf. phase1: d[t] via LDS float atomics; reciprocal;
// V-scale by 1/d; phase2: QK+exp+PV per own s-tile; epilogue gates via obuf.
#define KF    0
#define VF    32768
#define DRED  65536
#define ATTN_LDS 67584

__global__ __launch_bounds__(512,4) void attn_fused6(const u16* __restrict__ xhat,
      const u16* __restrict__ Wfrag, const float* __restrict__ ball,
      u16* __restrict__ obuf){
  extern __shared__ char sm[];
  const int bid = blockIdx.x;
  const int xcd = bid & 7, kk2 = bid >> 3;
  const int r = xcd*48 + (kk2 >> 3);     // 8 heads of one r consecutive on one XCD
  const int head = kk2 & 7;
  const int tid  = threadIdx.x;
  const int w    = tid >> 6;
  const int lane = tid & 63;
  const int gg = lane >> 5, j = lane & 31;
  const int n0 = r * 512;

  // zero d-accumulators (ordered vs phase-1 atomics by the post-proj barrier)
  {
    float* dred = (float*)(sm + DRED);
    dred[tid] = 0.f;
  }

  bf16x8 Qfr[2][2];   // own s-tiles' Q fragments (static indexing only)

  // ================= proj =================
  {
    const float* bb_base = ball + head*128;
    #pragma unroll
    for(int mat=0; mat<4; mat++){
      const u16* wsrc = Wfrag + ((size_t)((head*4+mat)*16)*64 + lane)*8;
      float biasv = (mat == 2) ? bb_base[64 + j] : 0.f;
      #pragma unroll
      for(int st=0; st<2; st++){
        const int stg = 2*w + st;
        const u16* xr = xhat + ((size_t)(n0 + stg*32 + j))*CM + gg*8;
        f32x16 D = zero16();
        if (mat == 2){
          #pragma unroll
          for(int kc=0;kc<16;kc++)
            D = MFMA32(*(const bf16x8*)(xr + kc*16),
                       *(const bf16x8*)(wsrc + (size_t)kc*512), D);
        } else {
          #pragma unroll
          for(int kc=0;kc<16;kc++)
            D = MFMA32(*(const bf16x8*)(wsrc + (size_t)kc*512),
                       *(const bf16x8*)(xr + kc*16), D);
        }
        if (mat == 3){                     // G: sigmoid -> obuf (gate staging)
          int srow = n0 + stg*32 + j;
          u32* ob32 = (u32*)(obuf + (size_t)srow*CM + head*32);
          #pragma unroll
          for(int p=0;p<4;p++)
            #pragma unroll
            for(int hh=0;hh<2;hh++){
              float2 bb = *(const float2*)(bb_base + 96 + 8*p + 2*hh + 4*gg);
              float a = D[4*p+2*hh]   + bb.x;
              float b = D[4*p+2*hh+1] + bb.y;
              ob32[4*p + 2*gg + hh] =
                  cvtpk(1.f/(1.f + __expf(-a)), 1.f/(1.f + __expf(-b)));
            }
        } else {
          u32 Wd[8];
          if (mat == 2){
            #pragma unroll
            for(int p=0;p<4;p++)
              #pragma unroll
              for(int hh=0;hh<2;hh++)
                Wd[p*2+hh] = cvtpk(D[4*p+2*hh] + biasv, D[4*p+2*hh+1] + biasv);
          } else {
            #pragma unroll
            for(int p=0;p<4;p++)
              #pragma unroll
              for(int hh=0;hh<2;hh++){
                float2 bb = *(const float2*)(bb_base + mat*32 + 8*p + 2*hh + 4*gg);
                Wd[p*2+hh] = cvtpk(D[4*p+2*hh] + bb.x, D[4*p+2*hh+1] + bb.y);
              }
          }
          u32 frag[2][4];
          #pragma unroll
          for(int T=0;T<2;T++)
            #pragma unroll
            for(int hh=0;hh<2;hh++){
              v2i res = pl32swap(Wd[4*T+hh], Wd[4*T+2+hh]);
              frag[T][hh] = (u32)res[0]; frag[T][2+hh] = (u32)res[1];
            }
          if (mat == 0){
            #pragma unroll
            for(int T=0;T<2;T++){
              union { u32 wu[4]; bf16x8 v; } u;
              u.wu[0]=frag[T][0]; u.wu[1]=frag[T][1]; u.wu[2]=frag[T][2]; u.wu[3]=frag[T][3];
              Qfr[st][T] = u.v;
            }
          } else {
            char* outbase = sm + (mat==1? KF : VF);
            #pragma unroll
            for(int T=0;T<2;T++)
              *(uint4*)(outbase + ((size_t)(stg*2+T)*64 + lane)*16) =
                  make_uint4(frag[T][0],frag[T][1],frag[T][2],frag[T][3]);
          }
        }
      }
    }
  }
  __syncthreads();

  // ================= phase 1: d[t] += partials via LDS atomics =========
  {
    float* dred = (float*)(sm + DRED);
    for(int tt=0; tt<16; tt++){
      bf16x8 Kt0 = *(const bf16x8*)(sm + KF + ((size_t)(tt*2+0)*64 + lane)*16);
      bf16x8 Kt1 = *(const bf16x8*)(sm + KF + ((size_t)(tt*2+1)*64 + lane)*16);
      float dp0 = 0.f, dp1 = 0.f;
      #pragma unroll
      for(int sb=0; sb<2; sb++){
        f32x16 D1 = zero16();
        D1 = MFMA32(Qfr[sb][0], Kt0, D1);   // D1[s][t] over c (K pre-scaled by SC2)
        D1 = MFMA32(Qfr[sb][1], Kt1, D1);
        #pragma unroll
        for(int q=0;q<16;q+=2){ dp0 += exp2f(D1[q]); dp1 += exp2f(D1[q+1]); }
      }
      float dp = dp0 + dp1;
      v2i rr = pl32swap(__float_as_uint(dp), __float_as_uint(dp));
      float tot = __uint_as_float((u32)rr[0]) + __uint_as_float((u32)rr[1]);
      if (lane < 32) atomicAdd(&dred[tt*32 + j], tot);
    }
  }
  __syncthreads();
  {
    float* dred = (float*)(sm + DRED);
    dred[tid] = 1.f / dred[tid];
  }
  __syncthreads();

  // ================= scale V-frags by ivd[t] =================
  {
    const float* ivd = (const float*)(sm + DRED);
    #pragma unroll
    for(int it=0; it<4; it++){
      int ch = tid + it*512;
      int t0 = (ch>>7)*32 + ((ch>>6)&1)*16 + ((ch>>5)&1)*8;
      u32* pw = (u32*)(sm + VF + (size_t)ch*16);
      uint4 v = *(uint4*)pw;
      u32 wv[4] = {v.x, v.y, v.z, v.w};
      u32 nw[4];
      #pragma unroll
      for(int rr2=0;rr2<4;rr2++){
        float lo = lo16f(wv[rr2]) * ivd[t0 + 2*rr2];
        float hi = hi16f(wv[rr2]) * ivd[t0 + 2*rr2 + 1];
        nw[rr2] = cvtpk(lo, hi);
      }
      *(uint4*)pw = make_uint4(nw[0],nw[1],nw[2],nw[3]);
    }
  }
  __syncthreads();

  // ================= phase 2 + gated epilogue =================
  #pragma unroll
  for(int sb=0; sb<2; sb++){
    f32x16 O = zero16();
    for(int tt=0; tt<16; tt++){
      bf16x8 Kt0 = *(const bf16x8*)(sm + KF + ((size_t)(tt*2+0)*64 + lane)*16);
      bf16x8 Kt1 = *(const bf16x8*)(sm + KF + ((size_t)(tt*2+1)*64 + lane)*16);
      bf16x8 Vt0 = *(const bf16x8*)(sm + VF + ((size_t)(tt*2+0)*64 + lane)*16);
      bf16x8 Vt1 = *(const bf16x8*)(sm + VF + ((size_t)(tt*2+1)*64 + lane)*16);
      f32x16 D = zero16();
      D = MFMA32(Kt0, Qfr[sb][0], D);      // D[t][s] over c (pre-scaled)
      D = MFMA32(Kt1, Qfr[sb][1], D);
      u32 Wd[8];
      #pragma unroll
      for(int p=0;p<4;p++)
        #pragma unroll
        for(int hh=0;hh<2;hh++)
          Wd[p*2+hh] = cvtpk(exp2f(D[4*p+2*hh]), exp2f(D[4*p+2*hh+1]));
      union { u32 wu[4]; bf16x8 v; } pf0, pf1;
      #pragma unroll
      for(int hh=0;hh<2;hh++){
        v2i res = pl32swap(Wd[0+hh], Wd[2+hh]);
        pf0.wu[hh] = (u32)res[0]; pf0.wu[2+hh] = (u32)res[1];
        v2i res2 = pl32swap(Wd[4+hh], Wd[6+hh]);
        pf1.wu[hh] = (u32)res2[0]; pf1.wu[2+hh] = (u32)res2[1];
      }
      O = MFMA32(Vt0, pf0.v, O);
      O = MFMA32(Vt1, pf1.v, O);
    }
    // epilogue: read gate from obuf, multiply, overwrite
    const int stg = 2*w + sb;
    const int srow = n0 + stg*32 + j;
    u32* ob32 = (u32*)(obuf + (size_t)srow*CM + head*32);
    #pragma unroll
    for(int p=0;p<4;p++)
      #pragma unroll
      for(int hh=0;hh<2;hh++){
        u32 gv = ob32[4*p + 2*gg + hh];
        float o0 = O[4*p+2*hh]   * lo16f(gv);
        float o1 = O[4*p+2*hh+1] * hi16f(gv);
        ob32[4*p + 2*gg + hh] = cvtpk(o0, o1);
      }
  }
}

// --------------------------------------------------------------- outproj ----
__global__ __launch_bounds__(256,2) void outproj(const u16* __restrict__ obuf,
      const u16* __restrict__ oWhi, const u16* __restrict__ oWlo,
      const float* __restrict__ ob, float* __restrict__ out){
  const int tid = threadIdx.x, w = tid>>6, lane = tid&63, g = lane>>4, i = lane&15;
  const int n0 = blockIdx.x*64 + w*16;
  const char* ab = (const char*)(obuf + (size_t)(n0 + i)*CM);
  const f32x4 zf = {0.f,0.f,0.f,0.f};
  f32x4 acc[16];
  #pragma unroll
  for(int ct=0;ct<16;ct++) acc[ct] = zf;
  #pragma unroll
  for(int kk=0; kk<8; kk++){
    bf16x8 a = *(const bf16x8*)(ab + kk*64 + g*16);
    #pragma unroll
    for(int ct=0; ct<16; ct++){
      const char* wh = (const char*)(oWhi + (size_t)(ct*16 + i)*CM);
      const char* wl = (const char*)(oWlo + (size_t)(ct*16 + i)*CM);
      bf16x8 bh = *(const bf16x8*)(wh + kk*64 + g*16);
      bf16x8 bl = *(const bf16x8*)(wl + kk*64 + g*16);
      acc[ct] = MFMA16(a, bh, acc[ct]);
      acc[ct] = MFMA16(a, bl, acc[ct]);
    }
  }
  #pragma unroll
  for(int ct=0; ct<16; ct++){
    float bias = ob[ct*16 + i];
    #pragma unroll
    for(int q=0; q<4; q++){
      int n = n0 + 4*g + q;
      out[((size_t)(n & 511)*R_DIM + (n >> 9))*CM + ct*16 + i] = acc[ct][q] + bias;
    }
  }
}

// ------------------------------------------------------------------ host ----
extern "C" void kernel_launch(void* const* d_in, const int* in_sizes, int n_in,
                              void* d_out, int out_size, void* d_ws, size_t ws_size,
                              hipStream_t stream){
  const float* msa = (const float*)d_in[0];
  const float* lnw = (const float*)d_in[1];
  const float* lnb = (const float*)d_in[2];
  const float* Wq  = (const float*)d_in[3];
  const float* Wk  = (const float*)d_in[4];
  const float* Wv  = (const float*)d_in[5];
  const float* Wg  = (const float*)d_in[6];
  const float* oW  = (const float*)d_in[7];
  const float* ob  = (const float*)d_in[8];
  float* out = (float*)d_out;

  char* ws = (char*)d_ws;
  u16*   Wfrag  = (u16*)(ws);
  float* ball   = (float*)(ws + 524288);
  u16*   oWhi   = (u16*)(ws + 528384);
  u16*   oWlo   = (u16*)(ws + 659456);
  u16*   xhat   = (u16*)(ws + 790528);
  u16*   obuf   = (u16*)(ws + 101453824);

  (void)hipFuncSetAttribute((const void*)attn_fused6,
                      hipFuncAttributeMaxDynamicSharedMemorySize, ATTN_LDS);

  prep_w<<<dim3(1280), dim3(64), 0, stream>>>(lnw, lnb, Wq, Wk, Wv, Wg, oW,
                                              ball, Wfrag, oWhi, oWlo);
  ln_xhat<<<dim3(NROWS/64), dim3(256), 0, stream>>>(msa, xhat);
  attn_fused6<<<dim3(R_DIM*NH), dim3(512), ATTN_LDS, stream>>>(xhat, Wfrag, ball, obuf);
  outproj<<<dim3(NROWS/64), dim3(256), 0, stream>>>(obuf, oWhi, oWlo, ob, out);
}

// Round 11
// 1038.650 us; speedup vs baseline: 1.3029x; 1.3029x over previous
//
#include <hip/hip_runtime.h>
#include <hip/hip_bf16.h>

// MSAColumnAttention — R11: attn = R8 verbatim (proven 747us, no spill);
// outproj rewritten on MFMA32 with frag-ordered oW (hi/lo) -> reg-light,
// latency-tolerant. R9/R10 established attn is reg-file-capped (128 VGPR +
// ~128 AGPR = 2 waves/SIMD); stop chasing occupancy, cut the other 390us.
//
// 32x32x16 bf16 MFMA layouts (R4/R6-verified):
//   A[m][k]: lane(gg,j)=gg*32+j holds row m=j, k=8gg+e ; B likewise (col n=j)
//   D[m][n]: lane(gg,j) holds col n=j, rows m=(reg&3)+8*(reg>>2)+4*gg
// Fragment construction: 8x cvt_pk + 4x permlane32_swap per D-tile (verified).
//
// ws layout (total 202,117,120 B):
//   Wfrag [8][4][16 kc][64 lane][8 bf16] @0 (512 KB) | ball [1024] f32 @524288
//   oWfh [8 mtile][16 kc][64 lane][8] bf16 @528384 | oWfl @659456
//   xhat [196608][256] bf16 @790528 | obuf [196608][256] bf16 @101453824

#define S_DIM 512
#define R_DIM 384
#define CM    256
#define NH    8
#define NROWS (S_DIM*R_DIM)

typedef unsigned short u16;
typedef unsigned int   u32;
typedef short bf16x8 __attribute__((ext_vector_type(8)));
typedef float f32x4  __attribute__((ext_vector_type(4)));
typedef float f32x16 __attribute__((ext_vector_type(16)));
typedef int   v2i    __attribute__((ext_vector_type(2)));

#define MFMA32(a,b,c) __builtin_amdgcn_mfma_f32_32x32x16_bf16((a),(b),(c),0,0,0)

__device__ __forceinline__ float lo16f(u32 u){ return __uint_as_float(u << 16); }
__device__ __forceinline__ float hi16f(u32 u){ return __uint_as_float(u & 0xffff0000u); }
__device__ __forceinline__ float b2f(u16 x){ return __uint_as_float(((u32)x) << 16); }
__device__ __forceinline__ u16 f2bf(float f){
  u32 u = __float_as_uint(f);
  return (u16)((u + 0x7fffu + ((u >> 16) & 1u)) >> 16);   // RNE
}
__device__ __forceinline__ u32 pk2(float a, float b){
  return (u32)f2bf(a) | ((u32)f2bf(b) << 16);
}
__device__ __forceinline__ u32 cvtpk(float a, float b){
  u32 d;
  asm("v_cvt_pk_bf16_f32 %0, %1, %2" : "=v"(d) : "v"(a), "v"(b));
  return d;
}
__device__ __forceinline__ v2i pl32swap(u32 a, u32 b){
  return __builtin_amdgcn_permlane32_swap((int)a, (int)b, false, false);
}
__device__ __forceinline__ f32x16 zero16(){
  f32x16 z;
  #pragma unroll
  for(int q=0;q<16;q++) z[q]=0.f;
  return z;
}

#define SC2 0.2550348653f   // (1/sqrt(32)) * log2(e), applied in f32 after QK MFMA

// ---------------------------------------------------------------- prep_w ----
// blocks 0..1023 (h*128 + mat*32 + c): fold ln into W row, write FRAG-ORDERED
// Wfrag[h][mat][kc][lane=gg*32+c][8] bf16; ball as before.
// blocks 1024..1279: oW hi/lo split, FRAG-ORDERED oWfh/oWfl[mtile][kc][lane][8].
__global__ void prep_w(const float* __restrict__ lnw, const float* __restrict__ lnb,
                       const float* __restrict__ Wq, const float* __restrict__ Wk,
                       const float* __restrict__ Wv, const float* __restrict__ Wg,
                       const float* __restrict__ oW,
                       float* __restrict__ ball, u16* __restrict__ Wfrag,
                       u16* __restrict__ oWfh, u16* __restrict__ oWfl){
  int blk = blockIdx.x, t = threadIdx.x;
  // elements k(d) = 4t..4t+3 -> kc = t>>2, gg = (t>>1)&1, e0 = (t&1)*4
  int kc = t >> 2, gg = (t >> 1) & 1, e0 = (t & 1) * 4;
  if (blk < 1024){
    int h = blk >> 7, row = blk & 127, mat = row >> 5, c = row & 31;
    const float* Ws = (mat==0?Wq: mat==1?Wk: mat==2?Wv:Wg) + (size_t)(h*32+c)*CM;
    float4 w4 = ((const float4*)Ws)[t];
    float4 l4 = ((const float4*)(lnw + (size_t)h*CM))[t];
    float4 b4 = ((const float4*)(lnb + (size_t)h*CM))[t];
    u16* dst = Wfrag + ((size_t)(((blk>>5)*16 + kc))*64 + gg*32 + c)*8 + e0;  // blk>>5 = h*4+mat
    *(uint2*)dst = make_uint2(pk2(w4.x*l4.x, w4.y*l4.y), pk2(w4.z*l4.z, w4.w*l4.w));
    float p = w4.x*b4.x + w4.y*b4.y + w4.z*b4.z + w4.w*b4.w;
    #pragma unroll
    for(int off=32; off; off>>=1) p += __shfl_down(p, off);
    if(t==0) ball[blk] = p;
  } else {
    int m = blk - 1024;
    float4 w4 = ((const float4*)(oW + (size_t)m*CM))[t];
    u16 h0=f2bf(w4.x), h1=f2bf(w4.y), h2=f2bf(w4.z), h3=f2bf(w4.w);
    u16 l0=f2bf(w4.x-b2f(h0)), l1=f2bf(w4.y-b2f(h1));
    u16 l2=f2bf(w4.z-b2f(h2)), l3=f2bf(w4.w-b2f(h3));
    size_t idx = ((size_t)(((m>>5)*16 + kc))*64 + gg*32 + (m&31))*8 + e0;
    *(uint2*)(oWfh + idx) = make_uint2((u32)h0|((u32)h1<<16), (u32)h2|((u32)h3<<16));
    *(uint2*)(oWfl + idx) = make_uint2((u32)l0|((u32)l1<<16), (u32)l2|((u32)l3<<16));
  }
}

// ---------------------------------------------------------------- ln_xhat ----
__global__ __launch_bounds__(256) void ln_xhat(const float* __restrict__ msa,
                                               u16* __restrict__ xhat){
  const int tid = threadIdx.x;
  const int n0 = blockIdx.x*64;
  const int i = tid >> 2, p = tid & 3;
  const int n = n0 + i, rr = n >> 9, s = n & 511;
  const float* src = msa + ((size_t)s*R_DIM + rr)*CM + p*64;
  float x[64]; float sum=0.f, sq=0.f;
  #pragma unroll
  for(int j=0;j<64;j+=4){
    float4 v = *(const float4*)(src + j);
    x[j]=v.x; x[j+1]=v.y; x[j+2]=v.z; x[j+3]=v.w;
    sum += v.x+v.y+v.z+v.w;
    sq  += v.x*v.x + v.y*v.y + v.z*v.z + v.w*v.w;
  }
  sum += __shfl_xor(sum,1); sum += __shfl_xor(sum,2);
  sq  += __shfl_xor(sq,1);  sq  += __shfl_xor(sq,2);
  float mu = sum*(1.f/256.f);
  float rs = rsqrtf(sq*(1.f/256.f) - mu*mu + 1e-5f);
  u16* dst = xhat + (size_t)n*CM + p*64;
  #pragma unroll
  for(int j=0;j<64;j+=2)
    *(u32*)(dst + j) = pk2((x[j]-mu)*rs, (x[j+1]-mu)*rs);
}

// --------------------------------------------------------------- attn_fused4 ----
// R8 VERBATIM: 512 thr / 8 waves, (512,2) -> 128 VGPR, no spill.
// Wave w owns s-tiles {2w, 2w+1}. proj: Wf from Wfrag (L2-hot); Q->regs,
// K/V->LDS, G->obuf. phase1: per-wave partial d -> dred; reduce -> ivd.
// V-scale by ivd; phase2: QK+exp+PV per own s-tile; epilogue gates via obuf.
#define KF    0
#define VF    32768
#define DRED  65536
#define ATTN_LDS 81920

__global__ __launch_bounds__(512,2) void attn_fused4(const u16* __restrict__ xhat,
      const u16* __restrict__ Wfrag, const float* __restrict__ ball,
      u16* __restrict__ obuf){
  extern __shared__ char sm[];
  const int bid = blockIdx.x;
  const int xcd = bid & 7, kk2 = bid >> 3;
  const int r = xcd*48 + (kk2 >> 3);     // 8 heads of one r consecutive on one XCD
  const int head = kk2 & 7;
  const int tid  = threadIdx.x;
  const int w    = tid >> 6;
  const int lane = tid & 63;
  const int gg = lane >> 5, j = lane & 31;
  const int n0 = r * 512;

  bf16x8 Qfr[2][2];   // own s-tiles' Q fragments (static indexing only)

  // ================= proj =================
  {
    #pragma unroll
    for(int mat=0; mat<4; mat++){
      bf16x8 Wf[16];
      const u16* wsrc = Wfrag + ((size_t)((head*4+mat)*16)*64 + lane)*8;
      #pragma unroll
      for(int kc=0;kc<16;kc++) Wf[kc] = *(const bf16x8*)(wsrc + (size_t)kc*512);
      float bias16[16]; float biasv = 0.f;
      if (mat == 2) biasv = ball[head*128 + 64 + j];
      else {
        #pragma unroll
        for(int reg=0;reg<16;reg++)
          bias16[reg] = ball[head*128 + mat*32 + (reg&3) + 8*(reg>>2) + 4*gg];
      }
      #pragma unroll
      for(int st=0; st<2; st++){
        const int stg = 2*w + st;
        const u16* xr = xhat + ((size_t)(n0 + stg*32 + j))*CM + gg*8;
        f32x16 D = zero16();
        if (mat == 2){
          #pragma unroll
          for(int kc=0;kc<16;kc++) D = MFMA32(*(const bf16x8*)(xr + kc*16), Wf[kc], D);
        } else {
          #pragma unroll
          for(int kc=0;kc<16;kc++) D = MFMA32(Wf[kc], *(const bf16x8*)(xr + kc*16), D);
        }
        if (mat == 3){                     // G: sigmoid -> obuf (gate staging)
          u32 gw[8];
          #pragma unroll
          for(int p=0;p<4;p++)
            #pragma unroll
            for(int hh=0;hh<2;hh++){
              float a = D[4*p+2*hh]   + bias16[4*p+2*hh];
              float b = D[4*p+2*hh+1] + bias16[4*p+2*hh+1];
              gw[p*2+hh] = cvtpk(1.f/(1.f + __expf(-a)), 1.f/(1.f + __expf(-b)));
            }
          int srow = n0 + stg*32 + j;
          u32* ob32 = (u32*)(obuf + (size_t)srow*CM + head*32);
          #pragma unroll
          for(int p=0;p<4;p++)
            #pragma unroll
            for(int hh=0;hh<2;hh++)
              ob32[4*p + 2*gg + hh] = gw[p*2+hh];
        } else {
          if (mat == 2){
            #pragma unroll
            for(int q=0;q<16;q++) D[q] += biasv;
          } else {
            #pragma unroll
            for(int q=0;q<16;q++) D[q] += bias16[q];
          }
          u32 Wd[8];
          #pragma unroll
          for(int p=0;p<4;p++)
            #pragma unroll
            for(int hh=0;hh<2;hh++)
              Wd[p*2+hh] = cvtpk(D[4*p+2*hh], D[4*p+2*hh+1]);
          u32 frag[2][4];
          #pragma unroll
          for(int T=0;T<2;T++)
            #pragma unroll
            for(int hh=0;hh<2;hh++){
              v2i res = pl32swap(Wd[4*T+hh], Wd[4*T+2+hh]);
              frag[T][hh] = (u32)res[0]; frag[T][2+hh] = (u32)res[1];
            }
          if (mat == 0){
            #pragma unroll
            for(int T=0;T<2;T++){
              union { u32 wu[4]; bf16x8 v; } u;
              u.wu[0]=frag[T][0]; u.wu[1]=frag[T][1]; u.wu[2]=frag[T][2]; u.wu[3]=frag[T][3];
              Qfr[st][T] = u.v;
            }
          } else {
            char* outbase = sm + (mat==1? KF : VF);
            #pragma unroll
            for(int T=0;T<2;T++)
              *(uint4*)(outbase + ((size_t)(stg*2+T)*64 + lane)*16) =
                  make_uint4(frag[T][0],frag[T][1],frag[T][2],frag[T][3]);
          }
        }
      }
    }
  }
  __syncthreads();

  // ================= phase 1: per-wave partial d; reduce -> ivd =========
  {
    float* dred = (float*)(sm + DRED);
    for(int tt=0; tt<16; tt++){
      bf16x8 Kt0 = *(const bf16x8*)(sm + KF + ((size_t)(tt*2+0)*64 + lane)*16);
      bf16x8 Kt1 = *(const bf16x8*)(sm + KF + ((size_t)(tt*2+1)*64 + lane)*16);
      float dp = 0.f;
      #pragma unroll
      for(int sb=0; sb<2; sb++){
        f32x16 D1 = zero16();
        D1 = MFMA32(Qfr[sb][0], Kt0, D1);   // D1[s][t] over c
        D1 = MFMA32(Qfr[sb][1], Kt1, D1);
        #pragma unroll
        for(int q=0;q<16;q++) dp += exp2f(D1[q]*SC2);
      }
      v2i rr = pl32swap(__float_as_uint(dp), __float_as_uint(dp));
      float tot = __uint_as_float((u32)rr[0]) + __uint_as_float((u32)rr[1]);
      if (lane < 32) dred[w*512 + tt*32 + j] = tot;
    }
  }
  __syncthreads();
  {
    float* dred = (float*)(sm + DRED);
    float s = 0.f;
    #pragma unroll
    for(int ww=0; ww<8; ww++) s += dred[ww*512 + tid];
    dred[tid] = 1.f / s;                    // ivd overlays row 0
  }
  __syncthreads();

  // ================= scale V-frags by ivd[t] =================
  {
    const float* ivd = (const float*)(sm + DRED);
    #pragma unroll
    for(int it=0; it<4; it++){
      int ch = tid + it*512;
      int t0 = (ch>>7)*32 + ((ch>>6)&1)*16 + ((ch>>5)&1)*8;
      u32* pw = (u32*)(sm + VF + (size_t)ch*16);
      uint4 v = *(uint4*)pw;
      u32 wv[4] = {v.x, v.y, v.z, v.w};
      u32 nw[4];
      #pragma unroll
      for(int rr2=0;rr2<4;rr2++){
        float lo = lo16f(wv[rr2]) * ivd[t0 + 2*rr2];
        float hi = hi16f(wv[rr2]) * ivd[t0 + 2*rr2 + 1];
        nw[rr2] = cvtpk(lo, hi);
      }
      *(uint4*)pw = make_uint4(nw[0],nw[1],nw[2],nw[3]);
    }
  }
  __syncthreads();

  // ================= phase 2 + gated epilogue =================
  #pragma unroll
  for(int sb=0; sb<2; sb++){
    f32x16 O = zero16();
    for(int tt=0; tt<16; tt++){
      bf16x8 Kt0 = *(const bf16x8*)(sm + KF + ((size_t)(tt*2+0)*64 + lane)*16);
      bf16x8 Kt1 = *(const bf16x8*)(sm + KF + ((size_t)(tt*2+1)*64 + lane)*16);
      bf16x8 Vt0 = *(const bf16x8*)(sm + VF + ((size_t)(tt*2+0)*64 + lane)*16);
      bf16x8 Vt1 = *(const bf16x8*)(sm + VF + ((size_t)(tt*2+1)*64 + lane)*16);
      f32x16 D = zero16();
      D = MFMA32(Kt0, Qfr[sb][0], D);      // D[t][s] over c
      D = MFMA32(Kt1, Qfr[sb][1], D);
      u32 Wd[8];
      #pragma unroll
      for(int p=0;p<4;p++)
        #pragma unroll
        for(int hh=0;hh<2;hh++)
          Wd[p*2+hh] = cvtpk(exp2f(D[4*p+2*hh]*SC2), exp2f(D[4*p+2*hh+1]*SC2));
      union { u32 wu[4]; bf16x8 v; } pf0, pf1;
      #pragma unroll
      for(int hh=0;hh<2;hh++){
        v2i res = pl32swap(Wd[0+hh], Wd[2+hh]);
        pf0.wu[hh] = (u32)res[0]; pf0.wu[2+hh] = (u32)res[1];
        v2i res2 = pl32swap(Wd[4+hh], Wd[6+hh]);
        pf1.wu[hh] = (u32)res2[0]; pf1.wu[2+hh] = (u32)res2[1];
      }
      O = MFMA32(Vt0, pf0.v, O);
      O = MFMA32(Vt1, pf1.v, O);
    }
    // epilogue: read gate from obuf, multiply, overwrite
    const int stg = 2*w + sb;
    const int srow = n0 + stg*32 + j;
    u32* ob32 = (u32*)(obuf + (size_t)srow*CM + head*32);
    #pragma unroll
    for(int p=0;p<4;p++)
      #pragma unroll
      for(int hh=0;hh<2;hh++){
        u32 gv = ob32[4*p + 2*gg + hh];
        float o0 = O[4*p+2*hh]   * lo16f(gv);
        float o1 = O[4*p+2*hh+1] * hi16f(gv);
        ob32[4*p + 2*gg + hh] = cvtpk(o0, o1);
      }
  }
}

// --------------------------------------------------------------- outproj2 ----
// MFMA32, frag-ordered weights. 256 thr / 4 waves; wave w -> rows row0..row0+31.
// out[n -> (s,r)][m] = obuf[n][:] . (oWfh+oWfl)[m][:] + ob[m].
// A = obuf rows (L1-hot, reread per ct), B = oWfh/oWfl (L2-hot, 128KB each).
__global__ __launch_bounds__(256,4) void outproj2(const u16* __restrict__ obuf,
      const u16* __restrict__ oWfh, const u16* __restrict__ oWfl,
      const float* __restrict__ ob, float* __restrict__ out){
  const int tid = threadIdx.x, w = tid>>6, lane = tid&63;
  const int gg = lane>>5, j = lane&31;
  const int row0 = blockIdx.x*128 + w*32;
  const u16* arow = obuf + (size_t)(row0 + j)*CM + gg*8;
  #pragma unroll 2
  for(int ct=0; ct<8; ct++){
    f32x16 acc = zero16();
    const u16* bh = oWfh + ((size_t)(ct*16)*64 + lane)*8;
    const u16* bl = oWfl + ((size_t)(ct*16)*64 + lane)*8;
    #pragma unroll
    for(int kc=0; kc<16; kc++){
      bf16x8 a = *(const bf16x8*)(arow + kc*16);
      acc = MFMA32(a, *(const bf16x8*)(bh + (size_t)kc*512), acc);
      acc = MFMA32(a, *(const bf16x8*)(bl + (size_t)kc*512), acc);
    }
    float bias = ob[ct*32 + j];
    #pragma unroll
    for(int reg=0; reg<16; reg++){
      int n = row0 + (reg&3) + 8*(reg>>2) + 4*gg;
      out[((size_t)(n & 511)*R_DIM + (n >> 9))*CM + ct*32 + j] = acc[reg] + bias;
    }
  }
}

// ------------------------------------------------------------------ host ----
extern "C" void kernel_launch(void* const* d_in, const int* in_sizes, int n_in,
                              void* d_out, int out_size, void* d_ws, size_t ws_size,
                              hipStream_t stream){
  const float* msa = (const float*)d_in[0];
  const float* lnw = (const float*)d_in[1];
  const float* lnb = (const float*)d_in[2];
  const float* Wq  = (const float*)d_in[3];
  const float* Wk  = (const float*)d_in[4];
  const float* Wv  = (const float*)d_in[5];
  const float* Wg  = (const float*)d_in[6];
  const float* oW  = (const float*)d_in[7];
  const float* ob  = (const float*)d_in[8];
  float* out = (float*)d_out;

  char* ws = (char*)d_ws;
  u16*   Wfrag  = (u16*)(ws);
  float* ball   = (float*)(ws + 524288);
  u16*   oWfh   = (u16*)(ws + 528384);
  u16*   oWfl   = (u16*)(ws + 659456);
  u16*   xhat   = (u16*)(ws + 790528);
  u16*   obuf   = (u16*)(ws + 101453824);

  (void)hipFuncSetAttribute((const void*)attn_fused4,
                      hipFuncAttributeMaxDynamicSharedMemorySize, ATTN_LDS);

  prep_w<<<dim3(1280), dim3(64), 0, stream>>>(lnw, lnb, Wq, Wk, Wv, Wg, oW,
                                              ball, Wfrag, oWfh, oWfl);
  ln_xhat<<<dim3(NROWS/64), dim3(256), 0, stream>>>(msa, xhat);
  attn_fused4<<<dim3(R_DIM*NH), dim3(512), ATTN_LDS, stream>>>(xhat, Wfrag, ball, obuf);
  outproj2<<<dim3(NROWS/128), dim3(256), 0, stream>>>(obuf, oWfh, oWfl, ob, out);
}

// Round 12
// 1013.826 us; speedup vs baseline: 1.3348x; 1.0245x over previous
//
#include <hip/hip_runtime.h>
#include <hip/hip_bf16.h>

// MSAColumnAttention — R12: ILP push at fixed occupancy. R9-null proved attn is
// dependency-stall-bound (not VALU-issue-bound); R9/R10 proved occupancy is
// pinned at 8 waves/CU (80KB LDS -> 1 block; ~160 regs/wave). So: give the
// scheduler slack — __launch_bounds__(512,1) (reg headroom), #pragma unroll 2
// on phase1/phase2 t-tile loops (two chains in flight), SC2 folded into K
// (R9-proven numerics-safe).
//
// 32x32x16 bf16 MFMA layouts (R4/R6-verified):
//   A[m][k]: lane(gg,j)=gg*32+j holds row m=j, k=8gg+e ; B likewise (col n=j)
//   D[m][n]: lane(gg,j) holds col n=j, rows m=(reg&3)+8*(reg>>2)+4*gg
// Fragment construction: 8x cvt_pk + 4x permlane32_swap per D-tile (verified).
//
// ws layout (total 202,117,120 B):
//   Wfrag [8][4][16 kc][64 lane][8 bf16] @0 (512 KB) | ball [1024] f32 @524288
//   oWfh [8 mtile][16 kc][64 lane][8] bf16 @528384 | oWfl @659456
//   xhat [196608][256] bf16 @790528 | obuf [196608][256] bf16 @101453824

#define S_DIM 512
#define R_DIM 384
#define CM    256
#define NH    8
#define NROWS (S_DIM*R_DIM)

typedef unsigned short u16;
typedef unsigned int   u32;
typedef short bf16x8 __attribute__((ext_vector_type(8)));
typedef float f32x4  __attribute__((ext_vector_type(4)));
typedef float f32x16 __attribute__((ext_vector_type(16)));
typedef int   v2i    __attribute__((ext_vector_type(2)));

#define MFMA32(a,b,c) __builtin_amdgcn_mfma_f32_32x32x16_bf16((a),(b),(c),0,0,0)

__device__ __forceinline__ float lo16f(u32 u){ return __uint_as_float(u << 16); }
__device__ __forceinline__ float hi16f(u32 u){ return __uint_as_float(u & 0xffff0000u); }
__device__ __forceinline__ float b2f(u16 x){ return __uint_as_float(((u32)x) << 16); }
__device__ __forceinline__ u16 f2bf(float f){
  u32 u = __float_as_uint(f);
  return (u16)((u + 0x7fffu + ((u >> 16) & 1u)) >> 16);   // RNE
}
__device__ __forceinline__ u32 pk2(float a, float b){
  return (u32)f2bf(a) | ((u32)f2bf(b) << 16);
}
__device__ __forceinline__ u32 cvtpk(float a, float b){
  u32 d;
  asm("v_cvt_pk_bf16_f32 %0, %1, %2" : "=v"(d) : "v"(a), "v"(b));
  return d;
}
__device__ __forceinline__ v2i pl32swap(u32 a, u32 b){
  return __builtin_amdgcn_permlane32_swap((int)a, (int)b, false, false);
}
__device__ __forceinline__ f32x16 zero16(){
  f32x16 z;
  #pragma unroll
  for(int q=0;q<16;q++) z[q]=0.f;
  return z;
}

#define SC2 0.2550348653f   // (1/sqrt(32)) * log2(e), folded into K at prep (R9-proven)

// ---------------------------------------------------------------- prep_w ----
// blocks 0..1023 (h*128 + mat*32 + c): fold ln (and SC2 for K) into W row,
// write FRAG-ORDERED Wfrag[h][mat][kc][lane=gg*32+c][8] bf16; ball likewise.
// blocks 1024..1279: oW hi/lo split, FRAG-ORDERED oWfh/oWfl[mtile][kc][lane][8].
__global__ void prep_w(const float* __restrict__ lnw, const float* __restrict__ lnb,
                       const float* __restrict__ Wq, const float* __restrict__ Wk,
                       const float* __restrict__ Wv, const float* __restrict__ Wg,
                       const float* __restrict__ oW,
                       float* __restrict__ ball, u16* __restrict__ Wfrag,
                       u16* __restrict__ oWfh, u16* __restrict__ oWfl){
  int blk = blockIdx.x, t = threadIdx.x;
  // elements k(d) = 4t..4t+3 -> kc = t>>2, gg = (t>>1)&1, e0 = (t&1)*4
  int kc = t >> 2, gg = (t >> 1) & 1, e0 = (t & 1) * 4;
  if (blk < 1024){
    int h = blk >> 7, row = blk & 127, mat = row >> 5, c = row & 31;
    const float* Ws = (mat==0?Wq: mat==1?Wk: mat==2?Wv:Wg) + (size_t)(h*32+c)*CM;
    const float qs = (mat==1) ? SC2 : 1.f;   // fold softmax scale into K (f32, pre-round)
    float4 w4 = ((const float4*)Ws)[t];
    float4 l4 = ((const float4*)(lnw + (size_t)h*CM))[t];
    float4 b4 = ((const float4*)(lnb + (size_t)h*CM))[t];
    u16* dst = Wfrag + ((size_t)(((blk>>5)*16 + kc))*64 + gg*32 + c)*8 + e0;  // blk>>5 = h*4+mat
    *(uint2*)dst = make_uint2(pk2(qs*w4.x*l4.x, qs*w4.y*l4.y),
                              pk2(qs*w4.z*l4.z, qs*w4.w*l4.w));
    float p = w4.x*b4.x + w4.y*b4.y + w4.z*b4.z + w4.w*b4.w;
    #pragma unroll
    for(int off=32; off; off>>=1) p += __shfl_down(p, off);
    if(t==0) ball[blk] = qs*p;
  } else {
    int m = blk - 1024;
    float4 w4 = ((const float4*)(oW + (size_t)m*CM))[t];
    u16 h0=f2bf(w4.x), h1=f2bf(w4.y), h2=f2bf(w4.z), h3=f2bf(w4.w);
    u16 l0=f2bf(w4.x-b2f(h0)), l1=f2bf(w4.y-b2f(h1));
    u16 l2=f2bf(w4.z-b2f(h2)), l3=f2bf(w4.w-b2f(h3));
    size_t idx = ((size_t)(((m>>5)*16 + kc))*64 + gg*32 + (m&31))*8 + e0;
    *(uint2*)(oWfh + idx) = make_uint2((u32)h0|((u32)h1<<16), (u32)h2|((u32)h3<<16));
    *(uint2*)(oWfl + idx) = make_uint2((u32)l0|((u32)l1<<16), (u32)l2|((u32)l3<<16));
  }
}

// ---------------------------------------------------------------- ln_xhat ----
__global__ __launch_bounds__(256) void ln_xhat(const float* __restrict__ msa,
                                               u16* __restrict__ xhat){
  const int tid = threadIdx.x;
  const int n0 = blockIdx.x*64;
  const int i = tid >> 2, p = tid & 3;
  const int n = n0 + i, rr = n >> 9, s = n & 511;
  const float* src = msa + ((size_t)s*R_DIM + rr)*CM + p*64;
  float x[64]; float sum=0.f, sq=0.f;
  #pragma unroll
  for(int j=0;j<64;j+=4){
    float4 v = *(const float4*)(src + j);
    x[j]=v.x; x[j+1]=v.y; x[j+2]=v.z; x[j+3]=v.w;
    sum += v.x+v.y+v.z+v.w;
    sq  += v.x*v.x + v.y*v.y + v.z*v.z + v.w*v.w;
  }
  sum += __shfl_xor(sum,1); sum += __shfl_xor(sum,2);
  sq  += __shfl_xor(sq,1);  sq  += __shfl_xor(sq,2);
  float mu = sum*(1.f/256.f);
  float rs = rsqrtf(sq*(1.f/256.f) - mu*mu + 1e-5f);
  u16* dst = xhat + (size_t)n*CM + p*64;
  #pragma unroll
  for(int j=0;j<64;j+=2)
    *(u32*)(dst + j) = pk2((x[j]-mu)*rs, (x[j+1]-mu)*rs);
}

// --------------------------------------------------------------- attn_fused4 ----
// 512 thr / 8 waves, 1 block/CU (LDS-capped). (512,1): reg slack for the
// scheduler; occupancy can't drop (LDS caps blocks) unless usage >~256.
// Wave w owns s-tiles {2w, 2w+1}. proj: Wf from Wfrag (L2-hot); Q->regs,
// K/V->LDS, G->obuf. phase1: per-wave partial d -> dred; reduce -> ivd.
// V-scale by ivd; phase2: QK+exp+PV per own s-tile; epilogue gates via obuf.
#define KF    0
#define VF    32768
#define DRED  65536
#define ATTN_LDS 81920

__global__ __launch_bounds__(512,1) void attn_fused4(const u16* __restrict__ xhat,
      const u16* __restrict__ Wfrag, const float* __restrict__ ball,
      u16* __restrict__ obuf){
  extern __shared__ char sm[];
  const int bid = blockIdx.x;
  const int xcd = bid & 7, kk2 = bid >> 3;
  const int r = xcd*48 + (kk2 >> 3);     // 8 heads of one r consecutive on one XCD
  const int head = kk2 & 7;
  const int tid  = threadIdx.x;
  const int w    = tid >> 6;
  const int lane = tid & 63;
  const int gg = lane >> 5, j = lane & 31;
  const int n0 = r * 512;

  bf16x8 Qfr[2][2];   // own s-tiles' Q fragments (static indexing only)

  // ================= proj =================
  {
    #pragma unroll
    for(int mat=0; mat<4; mat++){
      bf16x8 Wf[16];
      const u16* wsrc = Wfrag + ((size_t)((head*4+mat)*16)*64 + lane)*8;
      #pragma unroll
      for(int kc=0;kc<16;kc++) Wf[kc] = *(const bf16x8*)(wsrc + (size_t)kc*512);
      float bias16[16]; float biasv = 0.f;
      if (mat == 2) biasv = ball[head*128 + 64 + j];
      else {
        #pragma unroll
        for(int reg=0;reg<16;reg++)
          bias16[reg] = ball[head*128 + mat*32 + (reg&3) + 8*(reg>>2) + 4*gg];
      }
      #pragma unroll
      for(int st=0; st<2; st++){
        const int stg = 2*w + st;
        const u16* xr = xhat + ((size_t)(n0 + stg*32 + j))*CM + gg*8;
        f32x16 D = zero16();
        if (mat == 2){
          #pragma unroll
          for(int kc=0;kc<16;kc++) D = MFMA32(*(const bf16x8*)(xr + kc*16), Wf[kc], D);
        } else {
          #pragma unroll
          for(int kc=0;kc<16;kc++) D = MFMA32(Wf[kc], *(const bf16x8*)(xr + kc*16), D);
        }
        if (mat == 3){                     // G: sigmoid -> obuf (gate staging)
          u32 gw[8];
          #pragma unroll
          for(int p=0;p<4;p++)
            #pragma unroll
            for(int hh=0;hh<2;hh++){
              float a = D[4*p+2*hh]   + bias16[4*p+2*hh];
              float b = D[4*p+2*hh+1] + bias16[4*p+2*hh+1];
              gw[p*2+hh] = cvtpk(1.f/(1.f + __expf(-a)), 1.f/(1.f + __expf(-b)));
            }
          int srow = n0 + stg*32 + j;
          u32* ob32 = (u32*)(obuf + (size_t)srow*CM + head*32);
          #pragma unroll
          for(int p=0;p<4;p++)
            #pragma unroll
            for(int hh=0;hh<2;hh++)
              ob32[4*p + 2*gg + hh] = gw[p*2+hh];
        } else {
          if (mat == 2){
            #pragma unroll
            for(int q=0;q<16;q++) D[q] += biasv;
          } else {
            #pragma unroll
            for(int q=0;q<16;q++) D[q] += bias16[q];
          }
          u32 Wd[8];
          #pragma unroll
          for(int p=0;p<4;p++)
            #pragma unroll
            for(int hh=0;hh<2;hh++)
              Wd[p*2+hh] = cvtpk(D[4*p+2*hh], D[4*p+2*hh+1]);
          u32 frag[2][4];
          #pragma unroll
          for(int T=0;T<2;T++)
            #pragma unroll
            for(int hh=0;hh<2;hh++){
              v2i res = pl32swap(Wd[4*T+hh], Wd[4*T+2+hh]);
              frag[T][hh] = (u32)res[0]; frag[T][2+hh] = (u32)res[1];
            }
          if (mat == 0){
            #pragma unroll
            for(int T=0;T<2;T++){
              union { u32 wu[4]; bf16x8 v; } u;
              u.wu[0]=frag[T][0]; u.wu[1]=frag[T][1]; u.wu[2]=frag[T][2]; u.wu[3]=frag[T][3];
              Qfr[st][T] = u.v;
            }
          } else {
            char* outbase = sm + (mat==1? KF : VF);
            #pragma unroll
            for(int T=0;T<2;T++)
              *(uint4*)(outbase + ((size_t)(stg*2+T)*64 + lane)*16) =
                  make_uint4(frag[T][0],frag[T][1],frag[T][2],frag[T][3]);
          }
        }
      }
    }
  }
  __syncthreads();

  // ================= phase 1: per-wave partial d; reduce -> ivd =========
  {
    float* dred = (float*)(sm + DRED);
    #pragma unroll 2
    for(int tt=0; tt<16; tt++){
      bf16x8 Kt0 = *(const bf16x8*)(sm + KF + ((size_t)(tt*2+0)*64 + lane)*16);
      bf16x8 Kt1 = *(const bf16x8*)(sm + KF + ((size_t)(tt*2+1)*64 + lane)*16);
      float dp = 0.f;
      #pragma unroll
      for(int sb=0; sb<2; sb++){
        f32x16 D1 = zero16();
        D1 = MFMA32(Qfr[sb][0], Kt0, D1);   // D1[s][t] over c (K pre-scaled by SC2)
        D1 = MFMA32(Qfr[sb][1], Kt1, D1);
        #pragma unroll
        for(int q=0;q<16;q++) dp += exp2f(D1[q]);
      }
      v2i rr = pl32swap(__float_as_uint(dp), __float_as_uint(dp));
      float tot = __uint_as_float((u32)rr[0]) + __uint_as_float((u32)rr[1]);
      if (lane < 32) dred[w*512 + tt*32 + j] = tot;
    }
  }
  __syncthreads();
  {
    float* dred = (float*)(sm + DRED);
    float s = 0.f;
    #pragma unroll
    for(int ww=0; ww<8; ww++) s += dred[ww*512 + tid];
    dred[tid] = 1.f / s;                    // ivd overlays row 0
  }
  __syncthreads();

  // ================= scale V-frags by ivd[t] =================
  {
    const float* ivd = (const float*)(sm + DRED);
    #pragma unroll
    for(int it=0; it<4; it++){
      int ch = tid + it*512;
      int t0 = (ch>>7)*32 + ((ch>>6)&1)*16 + ((ch>>5)&1)*8;
      u32* pw = (u32*)(sm + VF + (size_t)ch*16);
      uint4 v = *(uint4*)pw;
      u32 wv[4] = {v.x, v.y, v.z, v.w};
      u32 nw[4];
      #pragma unroll
      for(int rr2=0;rr2<4;rr2++){
        float lo = lo16f(wv[rr2]) * ivd[t0 + 2*rr2];
        float hi = hi16f(wv[rr2]) * ivd[t0 + 2*rr2 + 1];
        nw[rr2] = cvtpk(lo, hi);
      }
      *(uint4*)pw = make_uint4(nw[0],nw[1],nw[2],nw[3]);
    }
  }
  __syncthreads();

  // ================= phase 2 + gated epilogue =================
  #pragma unroll
  for(int sb=0; sb<2; sb++){
    f32x16 O = zero16();
    #pragma unroll 2
    for(int tt=0; tt<16; tt++){
      bf16x8 Kt0 = *(const bf16x8*)(sm + KF + ((size_t)(tt*2+0)*64 + lane)*16);
      bf16x8 Kt1 = *(const bf16x8*)(sm + KF + ((size_t)(tt*2+1)*64 + lane)*16);
      bf16x8 Vt0 = *(const bf16x8*)(sm + VF + ((size_t)(tt*2+0)*64 + lane)*16);
      bf16x8 Vt1 = *(const bf16x8*)(sm + VF + ((size_t)(tt*2+1)*64 + lane)*16);
      f32x16 D = zero16();
      D = MFMA32(Kt0, Qfr[sb][0], D);      // D[t][s] over c (pre-scaled)
      D = MFMA32(Kt1, Qfr[sb][1], D);
      u32 Wd[8];
      #pragma unroll
      for(int p=0;p<4;p++)
        #pragma unroll
        for(int hh=0;hh<2;hh++)
          Wd[p*2+hh] = cvtpk(exp2f(D[4*p+2*hh]), exp2f(D[4*p+2*hh+1]));
      union { u32 wu[4]; bf16x8 v; } pf0, pf1;
      #pragma unroll
      for(int hh=0;hh<2;hh++){
        v2i res = pl32swap(Wd[0+hh], Wd[2+hh]);
        pf0.wu[hh] = (u32)res[0]; pf0.wu[2+hh] = (u32)res[1];
        v2i res2 = pl32swap(Wd[4+hh], Wd[6+hh]);
        pf1.wu[hh] = (u32)res2[0]; pf1.wu[2+hh] = (u32)res2[1];
      }
      O = MFMA32(Vt0, pf0.v, O);
      O = MFMA32(Vt1, pf1.v, O);
    }
    // epilogue: read gate from obuf, multiply, overwrite
    const int stg = 2*w + sb;
    const int srow = n0 + stg*32 + j;
    u32* ob32 = (u32*)(obuf + (size_t)srow*CM + head*32);
    #pragma unroll
    for(int p=0;p<4;p++)
      #pragma unroll
      for(int hh=0;hh<2;hh++){
        u32 gv = ob32[4*p + 2*gg + hh];
        float o0 = O[4*p+2*hh]   * lo16f(gv);
        float o1 = O[4*p+2*hh+1] * hi16f(gv);
        ob32[4*p + 2*gg + hh] = cvtpk(o0, o1);
      }
  }
}

// --------------------------------------------------------------- outproj2 ----
// MFMA32, frag-ordered weights. 256 thr / 4 waves; wave w -> rows row0..row0+31.
__global__ __launch_bounds__(256,4) void outproj2(const u16* __restrict__ obuf,
      const u16* __restrict__ oWfh, const u16* __restrict__ oWfl,
      const float* __restrict__ ob, float* __restrict__ out){
  const int tid = threadIdx.x, w = tid>>6, lane = tid&63;
  const int gg = lane>>5, j = lane&31;
  const int row0 = blockIdx.x*128 + w*32;
  const u16* arow = obuf + (size_t)(row0 + j)*CM + gg*8;
  #pragma unroll 2
  for(int ct=0; ct<8; ct++){
    f32x16 acc = zero16();
    const u16* bh = oWfh + ((size_t)(ct*16)*64 + lane)*8;
    const u16* bl = oWfl + ((size_t)(ct*16)*64 + lane)*8;
    #pragma unroll
    for(int kc=0; kc<16; kc++){
      bf16x8 a = *(const bf16x8*)(arow + kc*16);
      acc = MFMA32(a, *(const bf16x8*)(bh + (size_t)kc*512), acc);
      acc = MFMA32(a, *(const bf16x8*)(bl + (size_t)kc*512), acc);
    }
    float bias = ob[ct*32 + j];
    #pragma unroll
    for(int reg=0; reg<16; reg++){
      int n = row0 + (reg&3) + 8*(reg>>2) + 4*gg;
      out[((size_t)(n & 511)*R_DIM + (n >> 9))*CM + ct*32 + j] = acc[reg] + bias;
    }
  }
}

// ------------------------------------------------------------------ host ----
extern "C" void kernel_launch(void* const* d_in, const int* in_sizes, int n_in,
                              void* d_out, int out_size, void* d_ws, size_t ws_size,
                              hipStream_t stream){
  const float* msa = (const float*)d_in[0];
  const float* lnw = (const float*)d_in[1];
  const float* lnb = (const float*)d_in[2];
  const float* Wq  = (const float*)d_in[3];
  const float* Wk  = (const float*)d_in[4];
  const float* Wv  = (const float*)d_in[5];
  const float* Wg  = (const float*)d_in[6];
  const float* oW  = (const float*)d_in[7];
  const float* ob  = (const float*)d_in[8];
  float* out = (float*)d_out;

  char* ws = (char*)d_ws;
  u16*   Wfrag  = (u16*)(ws);
  float* ball   = (float*)(ws + 524288);
  u16*   oWfh   = (u16*)(ws + 528384);
  u16*   oWfl   = (u16*)(ws + 659456);
  u16*   xhat   = (u16*)(ws + 790528);
  u16*   obuf   = (u16*)(ws + 101453824);

  (void)hipFuncSetAttribute((const void*)attn_fused4,
                      hipFuncAttributeMaxDynamicSharedMemorySize, ATTN_LDS);

  prep_w<<<dim3(1280), dim3(64), 0, stream>>>(lnw, lnb, Wq, Wk, Wv, Wg, oW,
                                              ball, Wfrag, oWfh, oWfl);
  ln_xhat<<<dim3(NROWS/64), dim3(256), 0, stream>>>(msa, xhat);
  attn_fused4<<<dim3(R_DIM*NH), dim3(512), ATTN_LDS, stream>>>(xhat, Wfrag, ball, obuf);
  outproj2<<<dim3(NROWS/128), dim3(256), 0, stream>>>(obuf, oWfh, oWfl, ob, out);
}